// Round 4
// baseline (1103.982 us; speedup 1.0000x reference)
//
#include <hip/hip_runtime.h>
#include <math.h>

#define B_ 4
#define S_ 2048
#define D_ 1024
#define F_ 4096
#define E_ 8
#define T_ 8192
#define LBW_ 0.01f
#define HROWS_ 17408  // sum of per-expert 128-padded counts <= 16384 + 8*127 = 17400

#define BUFB 32768    // bytes per LDS buffer: A 256x32x2 (16384) + B 256x32x2 (16384)
#define ABYTES 16384

typedef unsigned short u16;
typedef __attribute__((ext_vector_type(8))) short bf16x8;
typedef __attribute__((ext_vector_type(4))) float f32x4;

// async global->LDS, 16B per lane; LDS dest = wave-uniform base + lane*16
#define GLOAD16(gp, lp) __builtin_amdgcn_global_load_lds( \
    (const __attribute__((address_space(1))) void*)(gp),  \
    (__attribute__((address_space(3))) void*)(lp), 16, 0, 0)

__device__ __forceinline__ u16 f2b(float f) {
    unsigned u = __float_as_uint(f);
    u = (u + 0x7FFFu + ((u >> 16) & 1u)) >> 16;   // RNE f32 -> bf16
    return (u16)u;
}
__device__ __forceinline__ float gelu_f(float v) {
    return 0.5f * v * (1.0f + erff(v * 0.70710678118654752440f));
}

// ------- per-expert transpose + convert: src (R x C f32, row-major) -> dst (C x R bf16) -------
__global__ __launch_bounds__(256) void cvt_T_kernel(const float* __restrict__ src,
                                                    u16* __restrict__ dst, int R, int C) {
    __shared__ u16 t[64][72];
    const int e = blockIdx.z;
    const float* s = src + (size_t)e * R * C;
    u16* d = dst + (size_t)e * R * C;
    const int r0 = blockIdx.y * 64, c0 = blockIdx.x * 64;
    const int tid = threadIdx.x;
    {
        int rr = tid >> 2, cq = (tid & 3) * 16;
        #pragma unroll
        for (int j = 0; j < 16; j += 4) {
            float4 v = *(const float4*)(s + (size_t)(r0 + rr) * C + c0 + cq + j);
            t[cq + j + 0][rr] = f2b(v.x);
            t[cq + j + 1][rr] = f2b(v.y);
            t[cq + j + 2][rr] = f2b(v.z);
            t[cq + j + 3][rr] = f2b(v.w);
        }
    }
    __syncthreads();
    {
        int cr = tid >> 2, rq = (tid & 3) * 16;
        #pragma unroll
        for (int j = 0; j < 16; j += 8) {
            int4 pk; u16* pw = (u16*)&pk;
            #pragma unroll
            for (int jj = 0; jj < 8; ++jj) pw[jj] = t[cr][rq + j + jj];
            *(int4*)(d + (size_t)(c0 + cr) * R + r0 + rq + j) = pk;
        }
    }
}

// ------- gate: logits (f64), softmax, top-2, routing lists, loss partials; also x->bf16 -------
__global__ __launch_bounds__(64) void gate_kernel(
    const float* __restrict__ x, const float* __restrict__ ew,
    const float* __restrict__ gw, const float* __restrict__ gb,
    u16* __restrict__ xb,
    float* __restrict__ combine, int* __restrict__ idx, int* __restrict__ cnt,
    int* __restrict__ fcnt, float* __restrict__ psum)
{
    const int t = blockIdx.x, l = threadIdx.x;
    const float* xr = x + (size_t)t * D_;
    double acc[E_];
    #pragma unroll
    for (int e = 0; e < E_; ++e) acc[e] = 0.0;
    u16 xw[16];
    #pragma unroll
    for (int kk = 0; kk < 16; kk += 4) {
        float4 xv = *(const float4*)(xr + l * 16 + kk);
        float xs[4] = {xv.x, xv.y, xv.z, xv.w};
        #pragma unroll
        for (int j = 0; j < 4; ++j) {
            xw[kk + j] = f2b(xs[j]);
            const float* gr = gw + (size_t)(l * 16 + kk + j) * E_;
            float4 g0 = *(const float4*)(gr);
            float4 g1 = *(const float4*)(gr + 4);
            acc[0] += (double)xs[j] * g0.x;  acc[1] += (double)xs[j] * g0.y;
            acc[2] += (double)xs[j] * g0.z;  acc[3] += (double)xs[j] * g0.w;
            acc[4] += (double)xs[j] * g1.x;  acc[5] += (double)xs[j] * g1.y;
            acc[6] += (double)xs[j] * g1.z;  acc[7] += (double)xs[j] * g1.w;
        }
    }
    *(int4*)(xb + (size_t)t * D_ + l * 16)     = *(int4*)(xw);
    *(int4*)(xb + (size_t)t * D_ + l * 16 + 8) = *(int4*)(xw + 8);
    #pragma unroll
    for (int e = 0; e < E_; ++e) {
        #pragma unroll
        for (int m = 32; m > 0; m >>= 1) acc[e] += __shfl_xor(acc[e], m);
    }
    if (l == 0) {
        const int b = t / S_;
        double p[E_]; double mx = -1e300;
        #pragma unroll
        for (int e = 0; e < E_; ++e) {
            p[e] = acc[e] + (double)gb[e] + (double)ew[b * E_ + e];
            mx = fmax(mx, p[e]);
        }
        double s = 0.0;
        #pragma unroll
        for (int e = 0; e < E_; ++e) { p[e] = exp(p[e] - mx); s += p[e]; }
        double inv = 1.0 / s;
        #pragma unroll
        for (int e = 0; e < E_; ++e) p[e] *= inv;
        double m1 = -1.0; int e1 = 0;
        #pragma unroll
        for (int e = 0; e < E_; ++e) if (p[e] > m1) { m1 = p[e]; e1 = e; }
        double m2 = -1.0; int e2 = 0;
        #pragma unroll
        for (int e = 0; e < E_; ++e) if (e != e1 && p[e] > m2) { m2 = p[e]; e2 = e; }
        float c1 = (float)(m1 / (m1 + m2)), c2 = (float)(m2 / (m1 + m2));
        #pragma unroll
        for (int e = 0; e < E_; ++e)
            combine[t * E_ + e] = (e == e1) ? c1 : ((e == e2) ? c2 : 0.0f);
        int q1 = atomicAdd(&cnt[e1], 1); idx[e1 * T_ + q1] = t;
        int q2 = atomicAdd(&cnt[e2], 1); idx[e2 * T_ + q2] = t;
        atomicAdd(&fcnt[(t & 63) * E_ + e1], 1);
        #pragma unroll
        for (int e = 0; e < E_; ++e) atomicAdd(&psum[(t & 63) * E_ + e], (float)p[e]);
    }
}

__global__ void offsets_kernel(const int* __restrict__ cnt, int* __restrict__ off) {
    if (threadIdx.x == 0 && blockIdx.x == 0) {
        int o = 0;
        for (int e = 0; e < E_; ++e) { off[e] = o; o += ((cnt[e] + 127) >> 7) << 7; }
    }
}

// ---- fused-expert GEMM, 256x256 tile, BK=32, 3-buffer counted-vmcnt, expert->XCD swizzle ----
// IS_G1: A = xb gathered rows (K=1024), out = h (gelu+b1).  !IS_G1: A = h rows (K=4096), out += atomic.
// grid 1D: gid = e + 8*(tm + 32*tn); consecutive same-XCD blocks share (e, tn) -> B-strip L2-resident.
template<int NT, bool IS_G1>
__global__ __launch_bounds__(512, 2) void moe_gemm_kernel(
    const u16* __restrict__ Aglob, const u16* __restrict__ Wt,
    const float* __restrict__ bias, const float* __restrict__ combine,
    const int* __restrict__ idxAll, const int* __restrict__ cntAll,
    const int* __restrict__ off,
    u16* __restrict__ hOut, float* __restrict__ out)
{
    constexpr int KD = NT * 32;
    const int gid = blockIdx.x;
    const int e = gid & 7;
    const int tm = (gid >> 3) & 31;
    const int tn = gid >> 8;
    const int cnt = cntAll[e];
    if (tm * 256 >= cnt) return;
    const int base = off[e];
    const int* idx_e = idxAll + e * T_;
    const u16* Bsrc = Wt + (size_t)e * ((size_t)D_ * F_);

    __shared__ __align__(16) char ldsr[3 * BUFB];

    const int tid = threadIdx.x;
    const int l = tid & 63, wid = tid >> 6;
    const int wm = (wid >> 2) * 128, wn = (wid & 3) * 64;   // wave tile 128x64 within 256x256
    const int lr = l & 15, lg = (l >> 4) & 3;

    // ---- stage source pointers. LDS slot (row, c) holds global chunk c ^ s(row),
    //      s(row) = (row&3)^((row>>2)&3). Lane l of gload: row = W + (l>>2), c = l&3. ----
    const int lrow = l >> 2;                             // row within 16-row wave slab
    const int cS8 = (((l & 3) ^ ((l >> 2) & 3) ^ ((l >> 4) & 3)) << 3);  // src chunk * 8 elems
    const u16* aptr[2]; const u16* bptr[2];
    #pragma unroll
    for (int i = 0; i < 2; ++i) {
        int row = i * 128 + wid * 16 + lrow;             // 0..255
        int r = tm * 256 + row;
        if (IS_G1) {
            int tok = (r < cnt) ? idx_e[r] : idx_e[0];
            aptr[i] = Aglob + (size_t)tok * KD + cS8;
        } else {
            int hr = base + r; if (hr > HROWS_ - 1) hr = HROWS_ - 1;  // clamp tail straddle
            aptr[i] = Aglob + (size_t)hr * KD + cS8;
        }
        bptr[i] = Bsrc + (size_t)(tn * 256 + row) * KD + cS8;
    }
    const int wof = wid * 1024;                          // wave-uniform LDS slab offset

    f32x4 acc[8][4];
    #pragma unroll
    for (int mi = 0; mi < 8; ++mi)
        #pragma unroll
        for (int ni = 0; ni < 4; ++ni)
            acc[mi][ni] = (f32x4){0.f, 0.f, 0.f, 0.f};

    auto stage = [&](int sb, int kofe) {
        GLOAD16(aptr[0] + kofe, ldsr + sb + wof);
        GLOAD16(aptr[1] + kofe, ldsr + sb + wof + 8192);
        GLOAD16(bptr[0] + kofe, ldsr + sb + ABYTES + wof);
        GLOAD16(bptr[1] + kofe, ldsr + sb + ABYTES + wof + 8192);
    };

    // prologue: stage tiles 0,1; drain tile 0 (tile 1's 4 loads stay in flight)
    stage(0, 0);
    stage(BUFB, 32);
    asm volatile("s_waitcnt vmcnt(4)" ::: "memory");
    __builtin_amdgcn_s_barrier();

    const int koff = ((lg ^ (lr & 3) ^ ((lr >> 2) & 3)) << 4);  // swizzled 16B chunk on read
    int cb = 0, sb2 = 2 * BUFB;
    int kofe = 64;
    for (int t = 0; t < NT; ++t) {
        // 1) frag ds_reads (conflict-floor via XOR swizzle)
        bf16x8 af[8], bfv[4];
        #pragma unroll
        for (int mi = 0; mi < 8; ++mi)
            af[mi] = *(const bf16x8*)(ldsr + cb + (wm + mi * 16 + lr) * 64 + koff);
        #pragma unroll
        for (int ni = 0; ni < 4; ++ni)
            bfv[ni] = *(const bf16x8*)(ldsr + cb + ABYTES + (wn + ni * 16 + lr) * 64 + koff);
        // 2) issue stage of tile t+2
        if (t < NT - 2) { stage(sb2, kofe); kofe += 32; }
        // 3) MFMA cluster
        __builtin_amdgcn_s_setprio(1);
        #pragma unroll
        for (int mi = 0; mi < 8; ++mi)
            #pragma unroll
            for (int ni = 0; ni < 4; ++ni)
                acc[mi][ni] = __builtin_amdgcn_mfma_f32_16x16x32_bf16(af[mi], bfv[ni], acc[mi][ni], 0, 0, 0);
        __builtin_amdgcn_s_setprio(0);
        // 4) counted wait: drain tile t+1's 4 loads; keep t+2's 4 in flight across barrier
        if (t < NT - 2)       { asm volatile("s_waitcnt vmcnt(4)" ::: "memory"); }
        else if (t == NT - 2) { asm volatile("s_waitcnt vmcnt(0)" ::: "memory"); }
        if (t < NT - 1) __builtin_amdgcn_s_barrier();
        cb += BUFB;  if (cb == 3 * BUFB)  cb = 0;
        sb2 += BUFB; if (sb2 == 3 * BUFB) sb2 = 0;
    }

    // ---- epilogue: C/D frag (row = lg*4+j, col = lr) ----
    if (IS_G1) {
        const float* be = bias + e * F_;
        const int pad = ((cnt + 127) >> 7) << 7;
        #pragma unroll
        for (int mi = 0; mi < 8; ++mi) {
            #pragma unroll
            for (int j = 0; j < 4; ++j) {
                int rl = tm * 256 + wm + mi * 16 + lg * 4 + j;
                if (rl < pad) {
                    size_t srow = (size_t)(base + rl) * F_;
                    #pragma unroll
                    for (int ni = 0; ni < 4; ++ni) {
                        int f = tn * 256 + wn + ni * 16 + lr;
                        hOut[srow + f] = f2b(gelu_f(acc[mi][ni][j] + be[f]));
                    }
                }
            }
        }
    } else {
        const float* be = bias + e * D_;
        #pragma unroll
        for (int mi = 0; mi < 8; ++mi) {
            #pragma unroll
            for (int j = 0; j < 4; ++j) {
                int rl = tm * 256 + wm + mi * 16 + lg * 4 + j;
                if (rl < cnt) {
                    int tkn = idx_e[rl];
                    float cw = combine[tkn * E_ + e];
                    float* orow = out + (size_t)tkn * D_;
                    #pragma unroll
                    for (int ni = 0; ni < 4; ++ni) {
                        int d = tn * 256 + wn + ni * 16 + lr;
                        atomicAdd(&orow[d], cw * (acc[mi][ni][j] + be[d]));
                    }
                }
            }
        }
    }
}

__global__ void loss_kernel(const int* __restrict__ fcnt, const float* __restrict__ psum,
                            float* __restrict__ dst) {
    if (threadIdx.x == 0 && blockIdx.x == 0) {
        float loss = 0.f;
        for (int e = 0; e < E_; ++e) {
            float fs = 0.f, Ps = 0.f;
            for (int s = 0; s < 64; ++s) { fs += (float)fcnt[s * E_ + e]; Ps += psum[s * E_ + e]; }
            loss += (fs / (float)T_) * (Ps / (float)T_);
        }
        *dst = LBW_ * (float)E_ * loss;
    }
}

__global__ void sentinel_kernel(float* __restrict__ dst) {
    if (threadIdx.x == 0) dst[0] = -12345.0f;
}

extern "C" void kernel_launch(void* const* d_in, const int* in_sizes, int n_in,
                              void* d_out, int out_size, void* d_ws, size_t ws_size,
                              hipStream_t stream)
{
    const float* x  = (const float*)d_in[0];
    const float* ew = (const float*)d_in[1];
    const float* gw = (const float*)d_in[2];
    const float* gb = (const float*)d_in[3];
    const float* w1 = (const float*)d_in[4];
    const float* b1 = (const float*)d_in[5];
    const float* w2 = (const float*)d_in[6];
    const float* b2 = (const float*)d_in[7];
    float* out = (float*)d_out;

    char* ws = (char*)d_ws;
    size_t o = 0;
    u16* w1t = (u16*)(ws + o); o += (size_t)E_ * D_ * F_ * 2;
    u16* w2t = (u16*)(ws + o); o += (size_t)E_ * F_ * D_ * 2;
    u16* xb  = (u16*)(ws + o); o += (size_t)T_ * D_ * 2;
    u16* h   = (u16*)(ws + o); o += (size_t)HROWS_ * F_ * 2;
    float* combine = (float*)(ws + o); o += (size_t)T_ * E_ * 4;
    int* idx = (int*)(ws + o); o += (size_t)E_ * T_ * 4;
    size_t zoff = o;
    int* cnt   = (int*)(ws + o); o += 128;
    int* fcnt  = (int*)(ws + o); o += 64 * E_ * 4;
    float* psum = (float*)(ws + o); o += 64 * E_ * 4;
    int* off   = (int*)(ws + o); o += 128;
    const size_t ws_needed = o;

    if (ws_size < ws_needed) {
        hipMemsetAsync(d_out, 0, (size_t)out_size * sizeof(float), stream);
        sentinel_kernel<<<1, 64, 0, stream>>>(out + (size_t)out_size - 1);
        return;
    }

    hipMemsetAsync(ws + zoff, 0, ws_needed - zoff, stream);
    hipMemsetAsync(d_out, 0, (size_t)out_size * sizeof(float), stream);

    cvt_T_kernel<<<dim3(F_ / 64, D_ / 64, E_), 256, 0, stream>>>(w1, w1t, D_, F_);
    cvt_T_kernel<<<dim3(D_ / 64, F_ / 64, E_), 256, 0, stream>>>(w2, w2t, F_, D_);
    gate_kernel<<<T_, 64, 0, stream>>>(x, ew, gw, gb, xb, combine, idx, cnt, fcnt, psum);
    offsets_kernel<<<1, 64, 0, stream>>>(cnt, off);
    // grid = E * Mtiles(32) * Ntiles ; e = gid&7 maps expert -> XCD, tm fast within XCD
    moe_gemm_kernel<32, true><<<8 * 32 * (F_ / 256), 512, 0, stream>>>(
        xb, w1t, b1, nullptr, idx, cnt, off, h, nullptr);
    moe_gemm_kernel<128, false><<<8 * 32 * (D_ / 256), 512, 0, stream>>>(
        h, w2t, b2, combine, idx, cnt, off, nullptr, out);
    loss_kernel<<<1, 64, 0, stream>>>(fcnt, psum, out + (size_t)out_size - 1);
}